// Round 1
// baseline (2622.625 us; speedup 1.0000x reference)
//
#include <hip/hip_runtime.h>
#include <hip/hip_bf16.h>

// Problem constants
#define B_SZ   8192
#define NNEI   20
#define DIN    256
#define GIN    128
#define HID    603
#define DOUT   256

__device__ __forceinline__ float wave_reduce_max(float v) {
#pragma unroll
  for (int off = 32; off >= 1; off >>= 1)
    v = fmaxf(v, __shfl_xor(v, off, 64));
  return v;
}
__device__ __forceinline__ float wave_reduce_sum(float v) {
#pragma unroll
  for (int off = 32; off >= 1; off >>= 1)
    v += __shfl_xor(v, off, 64);
  return v;
}

// One block per batch row b. Computes P[b,h] = pool over ROWS of
// act(A[b,row,:] @ W + bias). ACT=0: mean(relu(.)). ACT=1: mean(softmax_h(.))
// with A rows = ROWS-1 neighbor rows + 1 self row.
// Each thread owns 3 H-columns (c = tid, tid+256, tid+512), so softmax
// row-stats are block reductions and the pool lives in registers.
template <int ROWS, int K, int ACT>
__global__ __launch_bounds__(256) void pooled_hidden_kernel(
    const float* __restrict__ A_neigh,  // [B, ROWS_neigh, K]
    const float* __restrict__ A_self,   // [B, K] (ACT==1 only)
    const float* __restrict__ W,        // [K, HID]
    const float* __restrict__ bias,     // [HID]
    float* __restrict__ P)              // [B, HID]
{
  constexpr int NC = 3;
  __shared__ float As[ROWS][K];
  __shared__ float red[4];

  const int b = blockIdx.x;
  const int tid = threadIdx.x;

  // ---- stage A rows into LDS (vectorized, coalesced) ----
  constexpr int TOT_V4 = ROWS * K / 4;
  constexpr int NEIGH_V4 = (ACT == 1 ? (ROWS - 1) : ROWS) * K / 4;
  const float4* nv4 = (const float4*)A_neigh + (size_t)b * NEIGH_V4;
  float4* as4 = (float4*)&As[0][0];
  for (int i = tid; i < TOT_V4; i += 256) {
    float4 v;
    if (i < NEIGH_V4) {
      v = nv4[i];
    } else {
      v = ((const float4*)A_self)[(size_t)b * (K / 4) + (i - NEIGH_V4)];
    }
    as4[i] = v;
  }
  __syncthreads();

  // ---- per-thread columns ----
  int c[NC];
  int cc[NC];
  bool valid[NC];
  float bc[NC];
#pragma unroll
  for (int j = 0; j < NC; j++) {
    c[j] = tid + 256 * j;
    valid[j] = (c[j] < HID);
    cc[j] = valid[j] ? c[j] : (HID - 1);  // clamped (results discarded)
    bc[j] = bias[cc[j]];
  }

  float acc[ROWS][NC];
#pragma unroll
  for (int r = 0; r < ROWS; r++)
#pragma unroll
    for (int j = 0; j < NC; j++) acc[r][j] = 0.f;

  // ---- main GEMM loop: k-quads ----
  for (int k = 0; k < K; k += 4) {
    float w0[NC], w1[NC], w2[NC], w3[NC];
#pragma unroll
    for (int j = 0; j < NC; j++) {
      const float* wp = W + (size_t)k * HID + cc[j];
      w0[j] = wp[0];
      w1[j] = wp[HID];
      w2[j] = wp[2 * HID];
      w3[j] = wp[3 * HID];
    }
#pragma unroll
    for (int r = 0; r < ROWS; r++) {
      float4 a = *(const float4*)&As[r][k];  // broadcast across lanes
#pragma unroll
      for (int j = 0; j < NC; j++) {
        acc[r][j] = fmaf(a.x, w0[j], acc[r][j]);
        acc[r][j] = fmaf(a.y, w1[j], acc[r][j]);
        acc[r][j] = fmaf(a.z, w2[j], acc[r][j]);
        acc[r][j] = fmaf(a.w, w3[j], acc[r][j]);
      }
    }
  }

  // ---- activation + pool ----
  float pool[NC] = {0.f, 0.f, 0.f};

  if constexpr (ACT == 0) {
#pragma unroll
    for (int r = 0; r < ROWS; r++)
#pragma unroll
      for (int j = 0; j < NC; j++)
        pool[j] += fmaxf(acc[r][j] + bc[j], 0.f);
  } else {
    const int wid = tid >> 6;
    const int lane = tid & 63;
#pragma unroll
    for (int r = 0; r < ROWS; r++) {
      float v[NC];
#pragma unroll
      for (int j = 0; j < NC; j++)
        v[j] = valid[j] ? (acc[r][j] + bc[j]) : -1e30f;
      float m = fmaxf(v[0], fmaxf(v[1], v[2]));
      m = wave_reduce_max(m);
      if (lane == 0) red[wid] = m;
      __syncthreads();
      m = fmaxf(fmaxf(red[0], red[1]), fmaxf(red[2], red[3]));
      __syncthreads();
      float e[NC];
      float s = 0.f;
#pragma unroll
      for (int j = 0; j < NC; j++) {
        e[j] = valid[j] ? __expf(v[j] - m) : 0.f;
        s += e[j];
      }
      s = wave_reduce_sum(s);
      if (lane == 0) red[wid] = s;
      __syncthreads();
      s = red[0] + red[1] + red[2] + red[3];
      __syncthreads();
      float rz = 1.0f / s;
#pragma unroll
      for (int j = 0; j < NC; j++) pool[j] += e[j] * rz;
    }
  }

  const float scale = 1.0f / (float)ROWS;
#pragma unroll
  for (int j = 0; j < NC; j++)
    if (valid[j]) P[(size_t)b * HID + c[j]] = pool[j] * scale;
}

// Fused dual-GEMM: out[r, ooff+c] = relu(combine(A1@W1, A2@W2)), N=256 fixed.
// COMBINE 0: multiply, 1: add. BM=BN=64, BK=32, 256 threads, 4x4 micro-tile.
template <int COMBINE>
__global__ __launch_bounds__(256) void dual_gemm_kernel(
    const float* __restrict__ A1, int K1,
    const float* __restrict__ W1, int ldw1, int w1off,
    const float* __restrict__ A2, int K2,
    const float* __restrict__ W2, int ldw2, int w2off,
    float* __restrict__ out, int ldo, int ooff)
{
  __shared__ float Ats[32][68];  // transposed A tile, padded for b128 reads
  __shared__ float Ws[32][64];

  const int tid = threadIdx.x;
  const int tx = tid & 15;
  const int ty = tid >> 4;
  const int row0 = blockIdx.x * 64;
  const int col0 = blockIdx.y * 64;

  float acc1[4][4];
  float acc2[4][4];
#pragma unroll
  for (int i = 0; i < 4; i++)
#pragma unroll
    for (int j = 0; j < 4; j++) {
      acc1[i][j] = 0.f;
      acc2[i][j] = 0.f;
    }

  auto gemm_phase = [&](const float* __restrict__ A, int K,
                        const float* __restrict__ W, int ldw, int woff,
                        float (&acc)[4][4]) {
    for (int k0 = 0; k0 < K; k0 += 32) {
      __syncthreads();  // protect LDS from previous tile's readers
#pragma unroll
      for (int ii = 0; ii < 8; ii++) {
        int i = tid + ii * 256;
        int r = i >> 5;
        int k = i & 31;
        float v = (k0 + k < K) ? A[(size_t)(row0 + r) * K + k0 + k] : 0.f;
        Ats[k][r] = v;
      }
#pragma unroll
      for (int ii = 0; ii < 8; ii++) {
        int i = tid + ii * 256;
        int k = i >> 6;
        int cj = i & 63;
        float v = (k0 + k < K)
                      ? W[(size_t)(k0 + k) * ldw + woff + col0 + cj]
                      : 0.f;
        Ws[k][cj] = v;
      }
      __syncthreads();
#pragma unroll
      for (int kk = 0; kk < 32; kk++) {
        float4 a = *(const float4*)&Ats[kk][ty * 4];
        float4 w = *(const float4*)&Ws[kk][tx * 4];
        float av[4] = {a.x, a.y, a.z, a.w};
        float wv[4] = {w.x, w.y, w.z, w.w};
#pragma unroll
        for (int i2 = 0; i2 < 4; i2++)
#pragma unroll
          for (int j2 = 0; j2 < 4; j2++)
            acc[i2][j2] = fmaf(av[i2], wv[j2], acc[i2][j2]);
      }
    }
  };

  gemm_phase(A1, K1, W1, ldw1, w1off, acc1);
  gemm_phase(A2, K2, W2, ldw2, w2off, acc2);

#pragma unroll
  for (int i2 = 0; i2 < 4; i2++) {
    int r = row0 + ty * 4 + i2;
    float4 o;
    float vals[4];
#pragma unroll
    for (int j2 = 0; j2 < 4; j2++) {
      float v = (COMBINE == 0) ? acc1[i2][j2] * acc2[i2][j2]
                               : acc1[i2][j2] + acc2[i2][j2];
      vals[j2] = fmaxf(v, 0.f);
    }
    o.x = vals[0];
    o.y = vals[1];
    o.z = vals[2];
    o.w = vals[3];
    *(float4*)&out[(size_t)r * ldo + ooff + col0 + tx * 4] = o;
  }
}

extern "C" void kernel_launch(void* const* d_in, const int* in_sizes, int n_in,
                              void* d_out, int out_size, void* d_ws,
                              size_t ws_size, hipStream_t stream) {
  const float* self_vecs     = (const float*)d_in[0];   // [B, 256]
  const float* neigh_vecs    = (const float*)d_in[1];   // [B, 20, 256]
  const float* self_geto     = (const float*)d_in[2];   // [B, 128]
  const float* neigh_geto    = (const float*)d_in[3];   // [B, 20, 128]
  const float* W_feat        = (const float*)d_in[4];   // [256, 603]
  const float* b_feat        = (const float*)d_in[5];   // [603]
  const float* W_geto        = (const float*)d_in[6];   // [128, 603]
  const float* b_geto        = (const float*)d_in[7];   // [603]
  const float* W_concat      = (const float*)d_in[8];   // [128, 603]
  const float* b_concat      = (const float*)d_in[9];   // [603]
  const float* self_feat_w   = (const float*)d_in[10];  // [256, 256]
  const float* self_geto_w   = (const float*)d_in[11];  // [128, 256]
  const float* combined_geto = (const float*)d_in[12];  // [603, 512]
  const float* neigh_feat_w  = (const float*)d_in[13];  // [603, 256]
  const float* neigh_geto_w  = (const float*)d_in[14];  // [603, 256]
  float* out = (float*)d_out;

  float* P_concat = (float*)d_ws;                        // [B, 603]
  float* P_feat   = P_concat + (size_t)B_SZ * HID;       // [B, 603]
  float* P_geto   = P_feat + (size_t)B_SZ * HID;         // [B, 603]

  // Stage 1: pooled hiddens (no big intermediates; softmax fused in-block)
  pooled_hidden_kernel<21, GIN, 1><<<B_SZ, 256, 0, stream>>>(
      neigh_geto, self_geto, W_concat, b_concat, P_concat);
  pooled_hidden_kernel<20, DIN, 0><<<B_SZ, 256, 0, stream>>>(
      neigh_vecs, nullptr, W_feat, b_feat, P_feat);
  pooled_hidden_kernel<20, GIN, 0><<<B_SZ, 256, 0, stream>>>(
      neigh_geto, nullptr, W_geto, b_geto, P_geto);

  // Stage 2: fused projections + combine, writing d_out directly.
  dim3 g2(B_SZ / 64, DOUT / 64);
  // node_output[:, 0:256] = relu(from_geto[:,0:256] * (self_vecs@self_feat_w))
  dual_gemm_kernel<0><<<g2, 256, 0, stream>>>(
      P_concat, HID, combined_geto, 2 * DOUT, 0,
      self_vecs, DIN, self_feat_w, DOUT, 0,
      out, 2 * DOUT, 0);
  // node_output[:, 256:512] = relu(from_geto[:,256:512] * (P_feat@neigh_feat_w))
  dual_gemm_kernel<0><<<g2, 256, 0, stream>>>(
      P_concat, HID, combined_geto, 2 * DOUT, DOUT,
      P_feat, HID, neigh_feat_w, DOUT, 0,
      out, 2 * DOUT, DOUT);
  // geto_output = relu(self_geto@self_geto_w + P_geto@neigh_geto_w)
  dual_gemm_kernel<1><<<g2, 256, 0, stream>>>(
      self_geto, GIN, self_geto_w, DOUT, 0,
      P_geto, HID, neigh_geto_w, DOUT, 0,
      out + (size_t)B_SZ * 2 * DOUT, DOUT, 0);
}

// Round 2
// 1541.656 us; speedup vs baseline: 1.7012x; 1.7012x over previous
//
#include <hip/hip_runtime.h>
#include <hip/hip_bf16.h>

// Problem constants
#define B_SZ   8192
#define NNEI   20
#define DIN    256
#define GIN    128
#define HID    603
#define DOUT   256
#define NT_TOTAL 38   // ceil(603/16)

using short8  = __attribute__((ext_vector_type(8))) short;
using float4v = __attribute__((ext_vector_type(4))) float;

// ---------- bf16 helpers (header-version independent) ----------
__device__ __forceinline__ unsigned short f2bf_bits(float x) {
  unsigned int u = __builtin_bit_cast(unsigned int, x);
  unsigned int r = 0x7fffu + ((u >> 16) & 1u);   // RNE
  u += r;
  return (unsigned short)(u >> 16);
}
__device__ __forceinline__ float bf2f(unsigned short h) {
  unsigned int u = ((unsigned int)h) << 16;
  return __builtin_bit_cast(float, u);
}

// ---------- W pre-pack: fp32 [K][603] -> bf16 hi/lo in MFMA B-fragment order
// packed index p = ((nt*(K/8) + kb)*16 + c)*8 + j  stores W[kb*8+j][nt*16+c]
template <int K>
__global__ __launch_bounds__(256) void pack_w_kernel(
    const float* __restrict__ W, short* __restrict__ Wh, short* __restrict__ Wl) {
  constexpr int TOT = NT_TOTAL * (K / 8) * 16 * 8;
  int p = blockIdx.x * 256 + threadIdx.x;
  if (p >= TOT) return;
  int j  = p & 7;
  int cc = (p >> 3) & 15;
  int kb = (p >> 7) % (K / 8);
  int nt = p / (128 * (K / 8));
  int k   = kb * 8 + j;
  int col = nt * 16 + cc;
  float v = (col < HID) ? W[(size_t)k * HID + col] : 0.f;
  unsigned short h = f2bf_bits(v);
  float lo = v - bf2f(h);
  Wh[p] = (short)h;
  Wl[p] = (short)f2bf_bits(lo);
}

// ---------- fused stage-1: GEMM (MFMA, split-bf16) + act + mean-pool ----------
// One block per batch row b. Rows (20/21) padded to 32 = 2 M-tiles of 16.
// 38 N-tiles of 16 split across 4 waves (10/10/10/8).
// ACT=0: mean(relu(h+b)); ACT=1: mean over rows of softmax_cols(h+b).
// ACT==1: A rows = ROWS-1 neighbor rows + 1 self row (self is LAST row).
template <int ROWS, int K, int ACT>
__global__ __launch_bounds__(256) void pooled_mfma_kernel(
    const float* __restrict__ A_neigh,
    const float* __restrict__ A_self,
    const short* __restrict__ Wh,
    const short* __restrict__ Wl,
    const float* __restrict__ bias,
    float* __restrict__ P) {
  __shared__ short AsH[32][K];
  __shared__ short AsL[32][K];
  __shared__ float redA[4][32];
  __shared__ float redB[4][32];

  const int b    = blockIdx.x;
  const int tid  = threadIdx.x;
  const int w    = tid >> 6;
  const int lane = tid & 63;
  const int g    = lane >> 4;   // k-subgroup (0..3)
  const int c    = lane & 15;   // col-in-tile (B/C) == row-in-tile (A)

  // ---- stage A rows into LDS, splitting fp32 -> bf16 hi/lo ----
  constexpr int NEIGH_ROWS = (ACT == 1) ? (ROWS - 1) : ROWS;
  constexpr int NV4 = 32 * K / 4 / 256;
#pragma unroll
  for (int i = 0; i < NV4; i++) {
    int idx = tid + i * 256;          // float4 index over [32][K/4]
    int row = idx / (K / 4);
    int kq  = idx % (K / 4);
    float4 v = make_float4(0.f, 0.f, 0.f, 0.f);
    if (row < ROWS) {
      if (ACT == 1 && row == ROWS - 1)
        v = ((const float4*)A_self)[(size_t)b * (K / 4) + kq];
      else
        v = ((const float4*)A_neigh)[((size_t)b * NEIGH_ROWS + row) * (K / 4) + kq];
    }
    float x[4] = {v.x, v.y, v.z, v.w};
    ushort4 hh, ll;
    unsigned short* hp = &hh.x;
    unsigned short* lp = &ll.x;
#pragma unroll
    for (int q = 0; q < 4; q++) {
      unsigned short h = f2bf_bits(x[q]);
      hp[q] = h;
      lp[q] = f2bf_bits(x[q] - bf2f(h));
    }
    *(ushort4*)&AsH[row][kq * 4] = hh;
    *(ushort4*)&AsL[row][kq * 4] = ll;
  }
  __syncthreads();

  // ---- MFMA main loop ----
  constexpr int NTW = 10;
  const int nt0 = w * NTW;
  float4v acc[2][NTW];
#pragma unroll
  for (int mt = 0; mt < 2; mt++)
#pragma unroll
    for (int t = 0; t < NTW; t++) acc[mt][t] = (float4v){0.f, 0.f, 0.f, 0.f};

  for (int k0 = 0; k0 < K; k0 += 32) {
    short8 ah[2], al[2];
#pragma unroll
    for (int mt = 0; mt < 2; mt++) {
      ah[mt] = *(const short8*)&AsH[mt * 16 + c][k0 + 8 * g];
      al[mt] = *(const short8*)&AsL[mt * 16 + c][k0 + 8 * g];
    }
#pragma unroll
    for (int t = 0; t < NTW; t++) {
      int nt = nt0 + t;
      if (nt < NT_TOTAL) {
        const size_t base = (((size_t)nt * (K / 8) + (k0 / 8 + g)) * 16 + c) * 8;
        short8 wh = *(const short8*)&Wh[base];
        short8 wl = *(const short8*)&Wl[base];
#pragma unroll
        for (int mt = 0; mt < 2; mt++) {
          acc[mt][t] = __builtin_amdgcn_mfma_f32_16x16x32_bf16(ah[mt], wh, acc[mt][t], 0, 0, 0);
          acc[mt][t] = __builtin_amdgcn_mfma_f32_16x16x32_bf16(al[mt], wh, acc[mt][t], 0, 0, 0);
          acc[mt][t] = __builtin_amdgcn_mfma_f32_16x16x32_bf16(ah[mt], wl, acc[mt][t], 0, 0, 0);
        }
      }
    }
  }

  // ---- per-tile bias ----
  float bc[NTW];
#pragma unroll
  for (int t = 0; t < NTW; t++) {
    int nt = nt0 + t;
    int col = nt * 16 + c;
    bc[t] = (nt < NT_TOTAL && col < HID) ? bias[col] : 0.f;
  }

  // C/D layout: col = nt*16 + c ; row = mt*16 + g*4 + q
  if constexpr (ACT == 0) {
    float pool[NTW];
#pragma unroll
    for (int t = 0; t < NTW; t++) {
      float s = 0.f;
#pragma unroll
      for (int mt = 0; mt < 2; mt++)
#pragma unroll
        for (int q = 0; q < 4; q++) {
          int row = mt * 16 + g * 4 + q;
          if (row < ROWS) s += fmaxf(acc[mt][t][q] + bc[t], 0.f);
        }
      pool[t] = s;
    }
#pragma unroll
    for (int t = 0; t < NTW; t++) {
      pool[t] += __shfl_xor(pool[t], 16, 64);
      pool[t] += __shfl_xor(pool[t], 32, 64);
    }
    if (g == 0) {
#pragma unroll
      for (int t = 0; t < NTW; t++) {
        int nt = nt0 + t;
        int col = nt * 16 + c;
        if (nt < NT_TOTAL && col < HID)
          P[(size_t)b * HID + col] = pool[t] * (1.f / (float)ROWS);
      }
    }
  } else {
    // v = h + bias, invalid cols -> -inf
#pragma unroll
    for (int t = 0; t < NTW; t++) {
      int nt = nt0 + t;
      int col = nt * 16 + c;
      bool cv = (nt < NT_TOTAL) && (col < HID);
#pragma unroll
      for (int mt = 0; mt < 2; mt++)
#pragma unroll
        for (int q = 0; q < 4; q++)
          acc[mt][t][q] = cv ? (acc[mt][t][q] + bc[t]) : -1e30f;
    }
    // row max: per-lane over t, then across col-lanes (bits 0..3), then waves
    float rm[2][4];
#pragma unroll
    for (int mt = 0; mt < 2; mt++)
#pragma unroll
      for (int q = 0; q < 4; q++) {
        float m = -1e30f;
#pragma unroll
        for (int t = 0; t < NTW; t++) m = fmaxf(m, acc[mt][t][q]);
        rm[mt][q] = m;
      }
#pragma unroll
    for (int mt = 0; mt < 2; mt++)
#pragma unroll
      for (int q = 0; q < 4; q++) {
#pragma unroll
        for (int msk = 1; msk <= 8; msk <<= 1)
          rm[mt][q] = fmaxf(rm[mt][q], __shfl_xor(rm[mt][q], msk, 64));
      }
    if (c == 0) {
#pragma unroll
      for (int mt = 0; mt < 2; mt++)
#pragma unroll
        for (int q = 0; q < 4; q++) redA[w][mt * 16 + g * 4 + q] = rm[mt][q];
    }
    __syncthreads();
#pragma unroll
    for (int mt = 0; mt < 2; mt++)
#pragma unroll
      for (int q = 0; q < 4; q++) {
        int row = mt * 16 + g * 4 + q;
        rm[mt][q] = fmaxf(fmaxf(redA[0][row], redA[1][row]),
                          fmaxf(redA[2][row], redA[3][row]));
      }
    // e = exp(v - rm) into acc; row sums
    float rs[2][4] = {{0.f, 0.f, 0.f, 0.f}, {0.f, 0.f, 0.f, 0.f}};
#pragma unroll
    for (int t = 0; t < NTW; t++)
#pragma unroll
      for (int mt = 0; mt < 2; mt++)
#pragma unroll
        for (int q = 0; q < 4; q++) {
          float e = __expf(acc[mt][t][q] - rm[mt][q]);
          acc[mt][t][q] = e;
          rs[mt][q] += e;
        }
#pragma unroll
    for (int mt = 0; mt < 2; mt++)
#pragma unroll
      for (int q = 0; q < 4; q++) {
#pragma unroll
        for (int msk = 1; msk <= 8; msk <<= 1)
          rs[mt][q] += __shfl_xor(rs[mt][q], msk, 64);
      }
    if (c == 0) {
#pragma unroll
      for (int mt = 0; mt < 2; mt++)
#pragma unroll
        for (int q = 0; q < 4; q++) redB[w][mt * 16 + g * 4 + q] = rs[mt][q];
    }
    __syncthreads();
    float rinv[2][4];
#pragma unroll
    for (int mt = 0; mt < 2; mt++)
#pragma unroll
      for (int q = 0; q < 4; q++) {
        int row = mt * 16 + g * 4 + q;
        rinv[mt][q] = 1.f / (redB[0][row] + redB[1][row] + redB[2][row] + redB[3][row]);
      }
    // pool over valid rows
    float pool[NTW];
#pragma unroll
    for (int t = 0; t < NTW; t++) {
      float s = 0.f;
#pragma unroll
      for (int mt = 0; mt < 2; mt++)
#pragma unroll
        for (int q = 0; q < 4; q++) {
          int row = mt * 16 + g * 4 + q;
          if (row < ROWS) s += acc[mt][t][q] * rinv[mt][q];
        }
      pool[t] = s;
    }
#pragma unroll
    for (int t = 0; t < NTW; t++) {
      pool[t] += __shfl_xor(pool[t], 16, 64);
      pool[t] += __shfl_xor(pool[t], 32, 64);
    }
    if (g == 0) {
#pragma unroll
      for (int t = 0; t < NTW; t++) {
        int nt = nt0 + t;
        int col = nt * 16 + c;
        if (nt < NT_TOTAL && col < HID)
          P[(size_t)b * HID + col] = pool[t] * (1.f / (float)ROWS);
      }
    }
  }
}

// ---------- stage-2: fused dual-GEMM (fp32, unchanged from round 1) ----------
template <int COMBINE>
__global__ __launch_bounds__(256) void dual_gemm_kernel(
    const float* __restrict__ A1, int K1,
    const float* __restrict__ W1, int ldw1, int w1off,
    const float* __restrict__ A2, int K2,
    const float* __restrict__ W2, int ldw2, int w2off,
    float* __restrict__ out, int ldo, int ooff) {
  __shared__ float Ats[32][68];
  __shared__ float Ws[32][64];

  const int tid = threadIdx.x;
  const int tx = tid & 15;
  const int ty = tid >> 4;
  const int row0 = blockIdx.x * 64;
  const int col0 = blockIdx.y * 64;

  float acc1[4][4];
  float acc2[4][4];
#pragma unroll
  for (int i = 0; i < 4; i++)
#pragma unroll
    for (int j = 0; j < 4; j++) {
      acc1[i][j] = 0.f;
      acc2[i][j] = 0.f;
    }

  auto gemm_phase = [&](const float* __restrict__ A, int K,
                        const float* __restrict__ W, int ldw, int woff,
                        float (&acc)[4][4]) {
    for (int k0 = 0; k0 < K; k0 += 32) {
      __syncthreads();
#pragma unroll
      for (int ii = 0; ii < 8; ii++) {
        int i = tid + ii * 256;
        int r = i >> 5;
        int k = i & 31;
        float v = (k0 + k < K) ? A[(size_t)(row0 + r) * K + k0 + k] : 0.f;
        Ats[k][r] = v;
      }
#pragma unroll
      for (int ii = 0; ii < 8; ii++) {
        int i = tid + ii * 256;
        int k = i >> 6;
        int cj = i & 63;
        float v = (k0 + k < K) ? W[(size_t)(k0 + k) * ldw + woff + col0 + cj] : 0.f;
        Ws[k][cj] = v;
      }
      __syncthreads();
#pragma unroll
      for (int kk = 0; kk < 32; kk++) {
        float4 a = *(const float4*)&Ats[kk][ty * 4];
        float4 w = *(const float4*)&Ws[kk][tx * 4];
        float av[4] = {a.x, a.y, a.z, a.w};
        float wv[4] = {w.x, w.y, w.z, w.w};
#pragma unroll
        for (int i2 = 0; i2 < 4; i2++)
#pragma unroll
          for (int j2 = 0; j2 < 4; j2++)
            acc[i2][j2] = fmaf(av[i2], wv[j2], acc[i2][j2]);
      }
    }
  };

  gemm_phase(A1, K1, W1, ldw1, w1off, acc1);
  gemm_phase(A2, K2, W2, ldw2, w2off, acc2);

#pragma unroll
  for (int i2 = 0; i2 < 4; i2++) {
    int r = row0 + ty * 4 + i2;
    float4 o;
    float vals[4];
#pragma unroll
    for (int j2 = 0; j2 < 4; j2++) {
      float v = (COMBINE == 0) ? acc1[i2][j2] * acc2[i2][j2]
                               : acc1[i2][j2] + acc2[i2][j2];
      vals[j2] = fmaxf(v, 0.f);
    }
    o.x = vals[0]; o.y = vals[1]; o.z = vals[2]; o.w = vals[3];
    *(float4*)&out[(size_t)r * ldo + ooff + col0 + tx * 4] = o;
  }
}

extern "C" void kernel_launch(void* const* d_in, const int* in_sizes, int n_in,
                              void* d_out, int out_size, void* d_ws,
                              size_t ws_size, hipStream_t stream) {
  const float* self_vecs     = (const float*)d_in[0];
  const float* neigh_vecs    = (const float*)d_in[1];
  const float* self_geto     = (const float*)d_in[2];
  const float* neigh_geto    = (const float*)d_in[3];
  const float* W_feat        = (const float*)d_in[4];
  const float* b_feat        = (const float*)d_in[5];
  const float* W_geto        = (const float*)d_in[6];
  const float* b_geto        = (const float*)d_in[7];
  const float* W_concat      = (const float*)d_in[8];
  const float* b_concat      = (const float*)d_in[9];
  const float* self_feat_w   = (const float*)d_in[10];
  const float* self_geto_w   = (const float*)d_in[11];
  const float* combined_geto = (const float*)d_in[12];
  const float* neigh_feat_w  = (const float*)d_in[13];
  const float* neigh_geto_w  = (const float*)d_in[14];
  float* out = (float*)d_out;

  float* P_concat = (float*)d_ws;
  float* P_feat   = P_concat + (size_t)B_SZ * HID;
  float* P_geto   = P_feat + (size_t)B_SZ * HID;

  constexpr int WPF = NT_TOTAL * (DIN / 8) * 16 * 8;  // feat pack elems (K=256)
  constexpr int WPG = NT_TOTAL * (GIN / 8) * 16 * 8;  // geto/concat (K=128)
  short* Wh_feat = (short*)(P_geto + (size_t)B_SZ * HID);
  short* Wl_feat = Wh_feat + WPF;
  short* Wh_geto = Wl_feat + WPF;
  short* Wl_geto = Wh_geto + WPG;
  short* Wh_cc   = Wl_geto + WPG;
  short* Wl_cc   = Wh_cc + WPG;

  // ---- W pre-pack (every call; ws is re-poisoned by harness) ----
  pack_w_kernel<DIN><<<(WPF + 255) / 256, 256, 0, stream>>>(W_feat, Wh_feat, Wl_feat);
  pack_w_kernel<GIN><<<(WPG + 255) / 256, 256, 0, stream>>>(W_geto, Wh_geto, Wl_geto);
  pack_w_kernel<GIN><<<(WPG + 255) / 256, 256, 0, stream>>>(W_concat, Wh_cc, Wl_cc);

  // ---- stage 1: fused MFMA GEMM + act + pool ----
  pooled_mfma_kernel<21, GIN, 1><<<B_SZ, 256, 0, stream>>>(
      neigh_geto, self_geto, Wh_cc, Wl_cc, b_concat, P_concat);
  pooled_mfma_kernel<20, DIN, 0><<<B_SZ, 256, 0, stream>>>(
      neigh_vecs, nullptr, Wh_feat, Wl_feat, b_feat, P_feat);
  pooled_mfma_kernel<20, GIN, 0><<<B_SZ, 256, 0, stream>>>(
      neigh_geto, nullptr, Wh_geto, Wl_geto, b_geto, P_geto);

  // ---- stage 2: fused projections + combine ----
  dim3 g2(B_SZ / 64, DOUT / 64);
  dual_gemm_kernel<0><<<g2, 256, 0, stream>>>(
      P_concat, HID, combined_geto, 2 * DOUT, 0,
      self_vecs, DIN, self_feat_w, DOUT, 0,
      out, 2 * DOUT, 0);
  dual_gemm_kernel<0><<<g2, 256, 0, stream>>>(
      P_concat, HID, combined_geto, 2 * DOUT, DOUT,
      P_feat, HID, neigh_feat_w, DOUT, 0,
      out, 2 * DOUT, DOUT);
  dual_gemm_kernel<1><<<g2, 256, 0, stream>>>(
      self_geto, GIN, self_geto_w, DOUT, 0,
      P_geto, HID, neigh_geto_w, DOUT, 0,
      out + (size_t)B_SZ * 2 * DOUT, DOUT, 0);
}

// Round 3
// 1282.468 us; speedup vs baseline: 2.0450x; 1.2021x over previous
//
#include <hip/hip_runtime.h>
#include <hip/hip_bf16.h>

// Problem constants
#define B_SZ   8192
#define DIN    256
#define GIN    128
#define HID    603
#define DOUT   256
#define NT_TOTAL 38   // ceil(603/16)

using short8  = __attribute__((ext_vector_type(8))) short;
using float4v = __attribute__((ext_vector_type(4))) float;

#define MFMA16 __builtin_amdgcn_mfma_f32_16x16x32_bf16

// ---------- bf16 helpers ----------
__device__ __forceinline__ unsigned short f2bf_bits(float x) {  // RNE (pack kernel)
  unsigned int u = __builtin_bit_cast(unsigned int, x);
  unsigned int r = 0x7fffu + ((u >> 16) & 1u);
  u += r;
  return (unsigned short)(u >> 16);
}
__device__ __forceinline__ float bf2f(unsigned short h) {
  unsigned int u = ((unsigned int)h) << 16;
  return __builtin_bit_cast(float, u);
}
// pack hi16(f0) | hi16(f1)<<16 via v_perm_b32 (bf16 truncation)
__device__ __forceinline__ unsigned int pack_bf16_trunc(float f0, float f1) {
  return __builtin_amdgcn_perm(__builtin_bit_cast(unsigned int, f1),
                               __builtin_bit_cast(unsigned int, f0),
                               0x07060302u);
}

// ---------- W pre-pack: fp32 [K][603] -> bf16 hi/lo in MFMA B-fragment order
// p = ((nt*(K/8) + kb)*16 + c)*8 + j  stores W[kb*8+j][nt*16+c]   (verified R2)
template <int K>
__global__ __launch_bounds__(256) void pack_w_kernel(
    const float* __restrict__ W, short* __restrict__ Wh, short* __restrict__ Wl) {
  constexpr int TOT = NT_TOTAL * (K / 8) * 16 * 8;
  int p = blockIdx.x * 256 + threadIdx.x;
  if (p >= TOT) return;
  int j  = p & 7;
  int cc = (p >> 3) & 15;
  int kb = (p >> 7) % (K / 8);
  int nt = p / (128 * (K / 8));
  int k   = kb * 8 + j;
  int col = nt * 16 + cc;
  float v = (col < HID) ? W[(size_t)k * HID + col] : 0.f;
  unsigned short h = f2bf_bits(v);
  float lo = v - bf2f(h);
  Wh[p] = (short)h;
  Wl[p] = (short)f2bf_bits(lo);
}

// ---------- stage-1 relu branch: P[b,:] = mean_rows relu(A[b]@W + bias) ----
// NB batch rows per block (NB*ROWS == MT*16 exactly). 4 waves split N-tiles
// {10,10,10,8}. A fragments loaded straight from global, trunc-bf16 in-reg.
// Pooling via ds_add_f32 into pool[NB][609] (609 => bank-shifted per b).
template <int ROWS, int K, int NB, int MT>
__global__ __launch_bounds__(256, 3) void stage1_relu_kernel(
    const float* __restrict__ A,      // [B, ROWS, K]
    const short* __restrict__ Wh,     // packed bf16
    const float* __restrict__ bias,   // [HID]
    float* __restrict__ P) {          // [B, HID]
  constexpr int KS  = K / 32;
  constexpr int MTP = MT / 2;
  __shared__ float pool[NB][609];

  const int tid  = threadIdx.x;
  const int w    = tid >> 6;
  const int lane = tid & 63;
  const int g    = lane >> 4;   // k-subgroup
  const int c    = lane & 15;   // col-in-tile (B/C) == row-in-tile (A)
  const int bbase = blockIdx.x * NB;

  for (int i = tid; i < NB * 609; i += 256) (&pool[0][0])[i] = 0.f;
  __syncthreads();

  const int nt0 = w * 10;
  const int ntw = min(10, NT_TOTAL - nt0);

  for (int mtp = 0; mtp < MTP; mtp++) {
    // ---- A fragments: 2 M-tiles x KS k-steps, direct global -> bf16 ----
    short8 ah[2][KS];
    int b0i[2], b1i[2], spl[2];
#pragma unroll
    for (int m2 = 0; m2 < 2; m2++) {
      int row = (mtp * 2 + m2) * 16 + c;
      int bl  = row / ROWS;
      int rr  = row - bl * ROWS;
      const float* src = A + ((size_t)(bbase + bl) * ROWS + rr) * K + g * 8;
#pragma unroll
      for (int ks = 0; ks < KS; ks++) {
        float4 f0 = *(const float4*)(src + ks * 32);
        float4 f1 = *(const float4*)(src + ks * 32 + 4);
        union { unsigned int u[4]; short8 s; } r;
        r.u[0] = pack_bf16_trunc(f0.x, f0.y);
        r.u[1] = pack_bf16_trunc(f0.z, f0.w);
        r.u[2] = pack_bf16_trunc(f1.x, f1.y);
        r.u[3] = pack_bf16_trunc(f1.z, f1.w);
        ah[m2][ks] = r.s;
      }
      int r0 = (mtp * 2 + m2) * 16 + g * 4;   // first of this lane's 4 rows
      b0i[m2] = r0 / ROWS;
      b1i[m2] = (r0 + 3) / ROWS;
      spl[m2] = b1i[m2] * ROWS - r0;          // q < spl -> b0
    }

    for (int t = 0; t < ntw; t++) {
      int nt = nt0 + t;
      float4v acc[2];
#pragma unroll
      for (int m2 = 0; m2 < 2; m2++) acc[m2] = (float4v){0.f, 0.f, 0.f, 0.f};
      const short* wp = Wh + (((size_t)nt * (K / 8) + g) * 16 + c) * 8;
#pragma unroll
      for (int ks = 0; ks < KS; ks++) {
        short8 wf = *(const short8*)(wp + (size_t)ks * 512);
        acc[0] = MFMA16(ah[0][ks], wf, acc[0], 0, 0, 0);
        acc[1] = MFMA16(ah[1][ks], wf, acc[1], 0, 0, 0);
      }
      int col = nt * 16 + c;
      if (col < HID) {
        float bc = bias[col];
#pragma unroll
        for (int m2 = 0; m2 < 2; m2++) {
          float v[4];
#pragma unroll
          for (int q = 0; q < 4; q++) v[q] = fmaxf(acc[m2][q] + bc, 0.f);
          if (b0i[m2] == b1i[m2]) {
            atomicAdd(&pool[b0i[m2]][col], v[0] + v[1] + v[2] + v[3]);
          } else {
            float sA = 0.f, sB = 0.f;
#pragma unroll
            for (int q = 0; q < 4; q++) {
              if (q < spl[m2]) sA += v[q]; else sB += v[q];
            }
            atomicAdd(&pool[b0i[m2]][col], sA);
            atomicAdd(&pool[b1i[m2]][col], sB);
          }
        }
      }
    }
  }
  __syncthreads();
  for (int i = tid; i < NB * HID; i += 256) {
    int bl = i / HID, col = i - bl * HID;
    P[((size_t)(bbase + bl)) * HID + col] = pool[bl][col] * (1.f / (float)ROWS);
  }
}

// ---------- stage-1 softmax branch (concat): split-bf16 (3 MFMA) ----------
// NB=3 b's (63 rows + 1 pad = 4 M-tiles). Waves nt-split; softmax row stats
// need cross-wave combine via small LDS arrays (2 barriers per mt-pair).
template <int ROWS, int K, int NB, int MT>
__global__ __launch_bounds__(256, 2) void stage1_softmax_kernel(
    const float* __restrict__ An,     // [B, ROWS-1, K]
    const float* __restrict__ Asf,    // [B, K] (self, last row)
    const short* __restrict__ Wh, const short* __restrict__ Wl,
    const float* __restrict__ bias,
    float* __restrict__ P) {
  constexpr int KS  = K / 32;   // 4
  constexpr int MTP = MT / 2;   // 2
  constexpr int NTW = 10;
  __shared__ float pool[NB][609];
  __shared__ float redm[4][32];
  __shared__ float reds[4][32];

  const int tid  = threadIdx.x;
  const int w    = tid >> 6;
  const int lane = tid & 63;
  const int g    = lane >> 4;
  const int c    = lane & 15;
  const int bbase = blockIdx.x * NB;

  for (int i = tid; i < NB * 609; i += 256) (&pool[0][0])[i] = 0.f;
  __syncthreads();

  const int nt0 = w * 10;
  const int ntw = min(10, NT_TOTAL - nt0);

  float bias_t[NTW];
#pragma unroll
  for (int t = 0; t < NTW; t++) {
    int nt = nt0 + t, col = nt * 16 + c;
    bias_t[t] = (nt < NT_TOTAL && col < HID) ? bias[col] : 0.f;
  }

  for (int mtp = 0; mtp < MTP; mtp++) {
    // ---- A fragments hi/lo ----
    short8 ah[2][KS], al[2][KS];
    int b0i[2], b1i[2], spl[2];
#pragma unroll
    for (int m2 = 0; m2 < 2; m2++) {
      int row = (mtp * 2 + m2) * 16 + c;
      int bl  = row / ROWS;
      int rr  = row - bl * ROWS;
      int gb  = bbase + bl;
      bool valid = (bl < NB) && (gb < B_SZ);
      const float* src = (rr == ROWS - 1)
          ? (Asf + (size_t)gb * K + g * 8)
          : (An + ((size_t)gb * (ROWS - 1) + rr) * K + g * 8);
#pragma unroll
      for (int ks = 0; ks < KS; ks++) {
        float4 f0 = make_float4(0.f, 0.f, 0.f, 0.f);
        float4 f1 = make_float4(0.f, 0.f, 0.f, 0.f);
        if (valid) {
          f0 = *(const float4*)(src + ks * 32);
          f1 = *(const float4*)(src + ks * 32 + 4);
        }
        float fv[8] = {f0.x, f0.y, f0.z, f0.w, f1.x, f1.y, f1.z, f1.w};
        float hf[8], lf[8];
#pragma unroll
        for (int j = 0; j < 8; j++) {
          unsigned int hu = __builtin_bit_cast(unsigned int, fv[j]) & 0xFFFF0000u;
          hf[j] = __builtin_bit_cast(float, hu);
          lf[j] = fv[j] - hf[j];
        }
        union { unsigned int u[4]; short8 s; } rh, rl;
#pragma unroll
        for (int p = 0; p < 4; p++) {
          rh.u[p] = pack_bf16_trunc(hf[2 * p], hf[2 * p + 1]);
          rl.u[p] = pack_bf16_trunc(lf[2 * p], lf[2 * p + 1]);
        }
        ah[m2][ks] = rh.s;
        al[m2][ks] = rl.s;
      }
      int r0 = (mtp * 2 + m2) * 16 + g * 4;
      b0i[m2] = r0 / ROWS;
      b1i[m2] = (r0 + 3) / ROWS;
      spl[m2] = b1i[m2] * ROWS - r0;
    }

    // ---- MFMA: acc[m2][t] over wave's nt share ----
    float4v acc[2][NTW];
#pragma unroll
    for (int m2 = 0; m2 < 2; m2++)
#pragma unroll
      for (int t = 0; t < NTW; t++) acc[m2][t] = (float4v){0.f, 0.f, 0.f, 0.f};

#pragma unroll
    for (int t = 0; t < NTW; t++) {
      if (t < ntw) {
        int nt = nt0 + t;
        const short* wph = Wh + (((size_t)nt * (K / 8) + g) * 16 + c) * 8;
        const short* wpl = Wl + (((size_t)nt * (K / 8) + g) * 16 + c) * 8;
#pragma unroll
        for (int ks = 0; ks < KS; ks++) {
          short8 wh = *(const short8*)(wph + (size_t)ks * 512);
          short8 wl = *(const short8*)(wpl + (size_t)ks * 512);
#pragma unroll
          for (int m2 = 0; m2 < 2; m2++) {
            acc[m2][t] = MFMA16(ah[m2][ks], wh, acc[m2][t], 0, 0, 0);
            acc[m2][t] = MFMA16(al[m2][ks], wh, acc[m2][t], 0, 0, 0);
            acc[m2][t] = MFMA16(ah[m2][ks], wl, acc[m2][t], 0, 0, 0);
          }
        }
      }
    }

    // ---- softmax epilogue ----
    // v = acc + bias (invalid cols -> -inf)
#pragma unroll
    for (int m2 = 0; m2 < 2; m2++)
#pragma unroll
      for (int t = 0; t < NTW; t++) {
        if (t < ntw) {
          int col = (nt0 + t) * 16 + c;
          bool cv = col < HID;
#pragma unroll
          for (int q = 0; q < 4; q++)
            acc[m2][t][q] = cv ? (acc[m2][t][q] + bias_t[t]) : -1e30f;
        }
      }
    // local row-max over t, reduce across c-lanes (bits 0..3)
    float rm[2][4];
#pragma unroll
    for (int m2 = 0; m2 < 2; m2++)
#pragma unroll
      for (int q = 0; q < 4; q++) {
        float m = -1e30f;
#pragma unroll
        for (int t = 0; t < NTW; t++)
          if (t < ntw) m = fmaxf(m, acc[m2][t][q]);
#pragma unroll
        for (int msk = 1; msk <= 8; msk <<= 1)
          m = fmaxf(m, __shfl_xor(m, msk, 64));
        rm[m2][q] = m;
      }
    if (c == 0) {
#pragma unroll
      for (int m2 = 0; m2 < 2; m2++)
#pragma unroll
        for (int q = 0; q < 4; q++) redm[w][m2 * 16 + g * 4 + q] = rm[m2][q];
    }
    __syncthreads();
#pragma unroll
    for (int m2 = 0; m2 < 2; m2++)
#pragma unroll
      for (int q = 0; q < 4; q++) {
        int idx = m2 * 16 + g * 4 + q;
        rm[m2][q] = fmaxf(fmaxf(redm[0][idx], redm[1][idx]),
                          fmaxf(redm[2][idx], redm[3][idx]));
      }
    // exp + local row-sum, reduce across c-lanes
    float rs[2][4];
#pragma unroll
    for (int m2 = 0; m2 < 2; m2++)
#pragma unroll
      for (int q = 0; q < 4; q++) {
        float s = 0.f;
#pragma unroll
        for (int t = 0; t < NTW; t++) {
          if (t < ntw) {
            float e = __expf(acc[m2][t][q] - rm[m2][q]);
            acc[m2][t][q] = e;
            s += e;
          }
        }
#pragma unroll
        for (int msk = 1; msk <= 8; msk <<= 1)
          s += __shfl_xor(s, msk, 64);
        rs[m2][q] = s;
      }
    if (c == 0) {
#pragma unroll
      for (int m2 = 0; m2 < 2; m2++)
#pragma unroll
        for (int q = 0; q < 4; q++) reds[w][m2 * 16 + g * 4 + q] = rs[m2][q];
    }
    __syncthreads();
    float rinv[2][4];
#pragma unroll
    for (int m2 = 0; m2 < 2; m2++)
#pragma unroll
      for (int q = 0; q < 4; q++) {
        int idx = m2 * 16 + g * 4 + q;
        rinv[m2][q] = 1.f / (reds[0][idx] + reds[1][idx] + reds[2][idx] + reds[3][idx]);
      }
    // pool (mean over rows of b): atomics per (t, m2)
#pragma unroll
    for (int t = 0; t < NTW; t++) {
      if (t < ntw) {
        int col = (nt0 + t) * 16 + c;
        if (col < HID) {
#pragma unroll
          for (int m2 = 0; m2 < 2; m2++) {
            float sA = 0.f, sB = 0.f;
#pragma unroll
            for (int q = 0; q < 4; q++) {
              float e = acc[m2][t][q] * rinv[m2][q];
              if (q < spl[m2]) sA += e; else sB += e;
            }
            bool vb0 = (b0i[m2] < NB) && (bbase + b0i[m2] < B_SZ);
            bool vb1 = (b1i[m2] < NB) && (bbase + b1i[m2] < B_SZ) &&
                       (b1i[m2] != b0i[m2]);
            if (vb0) atomicAdd(&pool[b0i[m2]][col], sA);
            if (vb1) atomicAdd(&pool[b1i[m2]][col], sB);
          }
        }
      }
    }
  }
  __syncthreads();
  for (int i = tid; i < NB * HID; i += 256) {
    int bl = i / HID, col = i - bl * HID;
    int gb = bbase + bl;
    if (gb < B_SZ)
      P[(size_t)gb * HID + col] = pool[bl][col] * (1.f / (float)ROWS);
  }
}

// ---------- stage-2: fused dual-GEMM (fp32, verified R1/R2) ----------
template <int COMBINE>
__global__ __launch_bounds__(256) void dual_gemm_kernel(
    const float* __restrict__ A1, int K1,
    const float* __restrict__ W1, int ldw1, int w1off,
    const float* __restrict__ A2, int K2,
    const float* __restrict__ W2, int ldw2, int w2off,
    float* __restrict__ out, int ldo, int ooff) {
  __shared__ float Ats[32][68];
  __shared__ float Ws[32][64];

  const int tid = threadIdx.x;
  const int tx = tid & 15;
  const int ty = tid >> 4;
  const int row0 = blockIdx.x * 64;
  const int col0 = blockIdx.y * 64;

  float acc1[4][4];
  float acc2[4][4];
#pragma unroll
  for (int i = 0; i < 4; i++)
#pragma unroll
    for (int j = 0; j < 4; j++) {
      acc1[i][j] = 0.f;
      acc2[i][j] = 0.f;
    }

  auto gemm_phase = [&](const float* __restrict__ A, int K,
                        const float* __restrict__ W, int ldw, int woff,
                        float (&acc)[4][4]) {
    for (int k0 = 0; k0 < K; k0 += 32) {
      __syncthreads();
#pragma unroll
      for (int ii = 0; ii < 8; ii++) {
        int i = tid + ii * 256;
        int r = i >> 5;
        int k = i & 31;
        float v = (k0 + k < K) ? A[(size_t)(row0 + r) * K + k0 + k] : 0.f;
        Ats[k][r] = v;
      }
#pragma unroll
      for (int ii = 0; ii < 8; ii++) {
        int i = tid + ii * 256;
        int k = i >> 6;
        int cj = i & 63;
        float v = (k0 + k < K) ? W[(size_t)(k0 + k) * ldw + woff + col0 + cj] : 0.f;
        Ws[k][cj] = v;
      }
      __syncthreads();
#pragma unroll
      for (int kk = 0; kk < 32; kk++) {
        float4 a = *(const float4*)&Ats[kk][ty * 4];
        float4 w = *(const float4*)&Ws[kk][tx * 4];
        float av[4] = {a.x, a.y, a.z, a.w};
        float wv[4] = {w.x, w.y, w.z, w.w};
#pragma unroll
        for (int i2 = 0; i2 < 4; i2++)
#pragma unroll
          for (int j2 = 0; j2 < 4; j2++)
            acc[i2][j2] = fmaf(av[i2], wv[j2], acc[i2][j2]);
      }
    }
  };

  gemm_phase(A1, K1, W1, ldw1, w1off, acc1);
  gemm_phase(A2, K2, W2, ldw2, w2off, acc2);

#pragma unroll
  for (int i2 = 0; i2 < 4; i2++) {
    int r = row0 + ty * 4 + i2;
    float4 o;
    float vals[4];
#pragma unroll
    for (int j2 = 0; j2 < 4; j2++) {
      float v = (COMBINE == 0) ? acc1[i2][j2] * acc2[i2][j2]
                               : acc1[i2][j2] + acc2[i2][j2];
      vals[j2] = fmaxf(v, 0.f);
    }
    o.x = vals[0]; o.y = vals[1]; o.z = vals[2]; o.w = vals[3];
    *(float4*)&out[(size_t)r * ldo + ooff + col0 + tx * 4] = o;
  }
}

extern "C" void kernel_launch(void* const* d_in, const int* in_sizes, int n_in,
                              void* d_out, int out_size, void* d_ws,
                              size_t ws_size, hipStream_t stream) {
  const float* self_vecs     = (const float*)d_in[0];
  const float* neigh_vecs    = (const float*)d_in[1];
  const float* self_geto     = (const float*)d_in[2];
  const float* neigh_geto    = (const float*)d_in[3];
  const float* W_feat        = (const float*)d_in[4];
  const float* b_feat        = (const float*)d_in[5];
  const float* W_geto        = (const float*)d_in[6];
  const float* b_geto        = (const float*)d_in[7];
  const float* W_concat      = (const float*)d_in[8];
  const float* b_concat      = (const float*)d_in[9];
  const float* self_feat_w   = (const float*)d_in[10];
  const float* self_geto_w   = (const float*)d_in[11];
  const float* combined_geto = (const float*)d_in[12];
  const float* neigh_feat_w  = (const float*)d_in[13];
  const float* neigh_geto_w  = (const float*)d_in[14];
  float* out = (float*)d_out;

  float* P_concat = (float*)d_ws;
  float* P_feat   = P_concat + (size_t)B_SZ * HID;
  float* P_geto   = P_feat + (size_t)B_SZ * HID;

  constexpr int WPF = NT_TOTAL * (DIN / 8) * 16 * 8;
  constexpr int WPG = NT_TOTAL * (GIN / 8) * 16 * 8;
  short* Wh_feat = (short*)(P_geto + (size_t)B_SZ * HID);
  short* Wl_feat = Wh_feat + WPF;
  short* Wh_geto = Wl_feat + WPF;
  short* Wl_geto = Wh_geto + WPG;
  short* Wh_cc   = Wl_geto + WPG;
  short* Wl_cc   = Wh_cc + WPG;

  // ---- W pre-pack ----
  pack_w_kernel<DIN><<<(WPF + 255) / 256, 256, 0, stream>>>(W_feat, Wh_feat, Wl_feat);
  pack_w_kernel<GIN><<<(WPG + 255) / 256, 256, 0, stream>>>(W_geto, Wh_geto, Wl_geto);
  pack_w_kernel<GIN><<<(WPG + 255) / 256, 256, 0, stream>>>(W_concat, Wh_cc, Wl_cc);

  // ---- stage 1 ----
  stage1_softmax_kernel<21, GIN, 3, 4><<<(B_SZ + 2) / 3, 256, 0, stream>>>(
      neigh_geto, self_geto, Wh_cc, Wl_cc, b_concat, P_concat);
  stage1_relu_kernel<20, DIN, 8, 10><<<B_SZ / 8, 256, 0, stream>>>(
      neigh_vecs, Wh_feat, b_feat, P_feat);
  stage1_relu_kernel<20, GIN, 8, 10><<<B_SZ / 8, 256, 0, stream>>>(
      neigh_geto, Wh_geto, b_geto, P_geto);

  // ---- stage 2 ----
  dim3 g2(B_SZ / 64, DOUT / 64);
  dual_gemm_kernel<0><<<g2, 256, 0, stream>>>(
      P_concat, HID, combined_geto, 2 * DOUT, 0,
      self_vecs, DIN, self_feat_w, DOUT, 0,
      out, 2 * DOUT, 0);
  dual_gemm_kernel<0><<<g2, 256, 0, stream>>>(
      P_concat, HID, combined_geto, 2 * DOUT, DOUT,
      P_feat, HID, neigh_feat_w, DOUT, 0,
      out, 2 * DOUT, DOUT);
  dual_gemm_kernel<1><<<g2, 256, 0, stream>>>(
      self_geto, GIN, self_geto_w, DOUT, 0,
      P_geto, HID, neigh_geto_w, DOUT, 0,
      out + (size_t)B_SZ * 2 * DOUT, DOUT, 0);
}